// Round 1
// baseline (245.915 us; speedup 1.0000x reference)
//
#include <hip/hip_runtime.h>
#include <hip/hip_bf16.h>

#define NB   4
#define MD   2048
#define KD   2048
#define ND   2048

// fallback (fused) kernel tile
#define BM   128
#define BN   128

typedef short bf16x8 __attribute__((ext_vector_type(8)));
typedef float f32x4  __attribute__((ext_vector_type(4)));
typedef unsigned int u32;

#define MFMA16(a, b, c) __builtin_amdgcn_mfma_f32_16x16x32_bf16(a, b, c, 0, 0, 0)
#define BAR()    __builtin_amdgcn_s_barrier()
#define PRIO(n)  __builtin_amdgcn_s_setprio(n)
#define WAITV(n) asm volatile("s_waitcnt vmcnt(" #n ")" ::: "memory")
#define WAITL(n) asm volatile("s_waitcnt lgkmcnt(" #n ")" ::: "memory")

// pack two fp32 -> one dword of 2 bf16 (RNE)
__device__ __forceinline__ unsigned pk2(float lo, float hi) {
    union { __hip_bfloat162 h2; unsigned u; } c;
    c.h2 = __float22bfloat162_rn(make_float2(lo, hi));
    return c.u;
}

__device__ __forceinline__ void gload_lds16(const void* g, void* l) {
    __builtin_amdgcn_global_load_lds(
        (const __attribute__((address_space(1))) u32*)g,
        (__attribute__((address_space(3))) u32*)l,
        16, 0, 0);
}

// ---- Phase 1 (fused): A fp32->bf16 cast  +  B[b][k][n] -> BT[b][n][k] bf16 ----
#define NCAST ((NB * MD * KD / 4) / 256)   // 16384 cast blocks (float4/thread)

__global__ __launch_bounds__(256) void prep_kernel(
    const float* __restrict__ A, const float* __restrict__ B,
    unsigned short* __restrict__ Abf, unsigned short* __restrict__ BT)
{
    __shared__ float t[64][65];   // transpose tile; +1 pad -> <=2-way conflicts (free)
    const int tid = threadIdx.x;

    if (blockIdx.x < NCAST) {
        const size_t idx = (size_t)blockIdx.x * 256 + tid;   // float4 index
        const float4 v = ((const float4*)A)[idx];
        uint2 w;
        w.x = pk2(v.x, v.y);
        w.y = pk2(v.z, v.w);
        ((uint2*)Abf)[idx] = w;
        return;
    }
    const int bx  = blockIdx.x - NCAST;      // 0..4095
    const int b   = bx >> 10;                // batch (1024 tiles per batch)
    const int rem = bx & 1023;
    const int k0  = (rem & 31) * 64;
    const int n0  = (rem >> 5) * 64;

    const float* Bb = B + (size_t)b * KD * ND;
    const int rk = tid >> 4;                 // 0..15, +16/pass
    const int rn = (tid & 15) * 4;
    #pragma unroll
    for (int p = 0; p < 4; ++p) {
        const int kl = p * 16 + rk;
        const float4 v = *(const float4*)(Bb + (size_t)(k0 + kl) * ND + n0 + rn);
        t[kl][rn + 0] = v.x; t[kl][rn + 1] = v.y;
        t[kl][rn + 2] = v.z; t[kl][rn + 3] = v.w;
    }
    __syncthreads();
    const int wn = tid >> 2;                 // 0..63 (owns column n)
    const int wk = (tid & 3) * 16;           // 16 consecutive k
    float f[16];
    #pragma unroll
    for (int j = 0; j < 16; ++j) f[j] = t[wk + j][wn];
    uint4 w0, w1;
    w0.x = pk2(f[0], f[1]);   w0.y = pk2(f[2], f[3]);
    w0.z = pk2(f[4], f[5]);   w0.w = pk2(f[6], f[7]);
    w1.x = pk2(f[8], f[9]);   w1.y = pk2(f[10], f[11]);
    w1.z = pk2(f[12], f[13]); w1.w = pk2(f[14], f[15]);
    unsigned short* dst = BT + (size_t)b * ND * KD + (size_t)(n0 + wn) * KD + k0 + wk;
    *(uint4*)(dst) = w0;
    *(uint4*)(dst + 8) = w1;
}

// ---------------------------------------------------------------------------
// Phase 2: 256x256 tile, BK=64, 8 waves (2M x 4N), 8-phase counted-vmcnt
// schedule (T2 swizzle + T3/T4 pipeline + T5 setprio).
//
// LDS: As/Bs[2][256][64] bf16 = 128 KiB. Buffer = tile parity.
// Swizzle: within a 128-B row of 8 16-B slots, physical slot = logical ^ (row&7).
//   Writes: global_load_lds dest stays LINEAR; the global SOURCE column is
//   pre-swizzled (rule #21). Reads: ds_read offset = (slot ^ (r&7))*16B.
// Stage unit: one half-tile (128 rows x 64 k) = 2 global_load_lds / thread.
// Per 8-phase iteration (tiles T even, T+1):
//   P1:A(T+1)h0  P2:A(T+1)h1  P3:B(T+2)h0  P4:B(T+2)h1 +vmcnt(4)
//   P5:A(T+2)h0  P6:A(T+2)h1  P7:B(T+3)h0  P8:B(T+3)h1 +vmcnt(4)
// Slot freeing: B slots are only read in P1/P5 (frags cached in regs); A slots
// are read through P4/P8. Every stage above targets a slot freed >=1 barrier
// earlier. vmcnt ledger (2 loads/stage): vmcnt(4) at P4 retires A(T+1)+older;
// at P8 retires B(T+2)+A(T+2); 4 loads (one B half-tile pair) stay in flight
// across the barrier -> never drains to 0 in the main loop.
// ---------------------------------------------------------------------------

__device__ __forceinline__ void lda_quad(const unsigned short* aR, const int qd,
                                         const int k0, const int k1,
                                         bf16x8& a00, bf16x8& a01,
                                         bf16x8& a10, bf16x8& a11)
{
    const unsigned short* p0 = aR + qd * (32 * 64);
    const unsigned short* p1 = p0 + 16 * 64;
    a00 = *(const bf16x8*)(p0 + k0);
    a01 = *(const bf16x8*)(p0 + k1);
    a10 = *(const bf16x8*)(p1 + k0);
    a11 = *(const bf16x8*)(p1 + k1);
}

__device__ __forceinline__ void ldb_all(const unsigned short* bR, const int k0, const int k1,
                                        bf16x8 (&b0)[4], bf16x8 (&b1)[4])
{
    #pragma unroll
    for (int n = 0; n < 4; ++n) {
        const unsigned short* p = bR + n * (16 * 64);
        b0[n] = *(const bf16x8*)(p + k0);
        b1[n] = *(const bf16x8*)(p + k1);
    }
}

__device__ __forceinline__ void mfma_quad(const bf16x8& a00, const bf16x8& a01,
                                          const bf16x8& a10, const bf16x8& a11,
                                          const bf16x8 (&b0)[4], const bf16x8 (&b1)[4],
                                          f32x4 (&c0)[4], f32x4 (&c1)[4])
{
    #pragma unroll
    for (int n = 0; n < 4; ++n) {
        c0[n] = MFMA16(a00, b0[n], c0[n]);
        c1[n] = MFMA16(a10, b0[n], c1[n]);
        c0[n] = MFMA16(a01, b1[n], c0[n]);
        c1[n] = MFMA16(a11, b1[n], c1[n]);
    }
}

// Stage one 128x64 half-tile: 2 x (64 rows x 128 B) rounds. LDS dest is
// linear (wave-uniform base + lane*16); source column is pre-swizzled.
#define STAGE_A(buf, half, tile) do {                                               \
    const size_t kgA_ = (size_t)(tile) * 64;                                        \
    gload_lds16(Abase + (size_t)((half) * 128      + s_row) * KD + kgA_ + s_col,    \
                &As[buf][(half) * 128     ][0] + wave512);                          \
    gload_lds16(Abase + (size_t)((half) * 128 + 64 + s_row) * KD + kgA_ + s_col,    \
                &As[buf][(half) * 128 + 64][0] + wave512);                          \
} while (0)

#define STAGE_B(buf, half, tile) do {                                               \
    const size_t kgB_ = (size_t)(tile) * 64;                                        \
    gload_lds16(Bbase + (size_t)((half) * 128      + s_row) * KD + kgB_ + s_col,    \
                &Bs[buf][(half) * 128     ][0] + wave512);                          \
    gload_lds16(Bbase + (size_t)((half) * 128 + 64 + s_row) * KD + kgB_ + s_col,    \
                &Bs[buf][(half) * 128 + 64][0] + wave512);                          \
} while (0)

__global__ __launch_bounds__(512, 2) void gemm256_kernel(
    const unsigned short* __restrict__ Abf, const unsigned short* __restrict__ BT,
    float* __restrict__ C)
{
    __shared__ __align__(16) unsigned short As[2][256][64];   // 64 KB
    __shared__ __align__(16) unsigned short Bs[2][256][64];   // 64 KB

    const int tid   = threadIdx.x;
    const int batch = blockIdx.z;
    const int row0  = blockIdx.y * 256;
    const int col0  = blockIdx.x * 256;

    const unsigned short* __restrict__ Abase =
        Abf + (size_t)batch * MD * KD + (size_t)row0 * KD;
    const unsigned short* __restrict__ Bbase =
        BT  + (size_t)batch * ND * KD + (size_t)col0 * KD;
    float* __restrict__ Cbase =
        C + (size_t)batch * MD * ND + (size_t)row0 * ND + col0;

    const int wave    = tid >> 6;
    const int lane    = tid & 63;
    const int q       = lane >> 4;          // 0..3
    const int r       = lane & 15;          // 0..15
    const int wm      = (wave >> 2) * 128;  // 0 / 128
    const int wn      = (wave & 3)  * 64;   // 0,64,128,192
    const int wave512 = wave * 512;         // elems: 1024 B per wave per 64-row round

    // staging geometry: per round 512 thr x 16 B = 64 rows x 128 B
    const int s_row = tid >> 3;                            // 0..63
    const int s_col = ((tid & 7) ^ (s_row & 7)) * 8;       // pre-swizzled src col (elems)

    // swizzled frag-read offsets (elems): logical slot ks*4+q -> ^ (r&7)
    const int rb    = r & 7;
    const int koff0 = ((q    ) ^ rb) * 8;                  // ks = 0
    const int koff1 = ((4 + q) ^ rb) * 8;                  // ks = 1

    const unsigned short* aR0 = &As[0][wm + r][0];
    const unsigned short* aR1 = &As[1][wm + r][0];
    const unsigned short* bR0 = &Bs[0][wn + r][0];
    const unsigned short* bR1 = &Bs[1][wn + r][0];

    f32x4 acc[8][4];
    #pragma unroll
    for (int m = 0; m < 8; ++m)
        #pragma unroll
        for (int n = 0; n < 4; ++n)
            acc[m][n] = (f32x4){0.f, 0.f, 0.f, 0.f};

    bf16x8 a00, a01, a10, a11;
    bf16x8 b0[4], b1[4];

    // prologue: tile0 A+B, tile1 B (A(1) is staged in P1/P2 of iteration 0)
    STAGE_A(0, 0, 0); STAGE_A(0, 1, 0);
    STAGE_B(0, 0, 0); STAGE_B(0, 1, 0);
    STAGE_B(1, 0, 1); STAGE_B(1, 1, 1);
    __syncthreads();                       // full drain once (prologue only)

    for (int it = 0; it < 15; ++it) {      // tiles T=2it, 2it+1 ; T <= 28
        const int T = it * 2;
        // ---- P1: tile T quad0 (+ B(T) frags), stage A(T+1) h0 ----
        ldb_all(bR0, koff0, koff1, b0, b1);
        lda_quad(aR0, 0, koff0, koff1, a00, a01, a10, a11);
        STAGE_A(1, 0, T + 1);
        WAITL(8); BAR(); WAITL(0);
        PRIO(1); mfma_quad(a00, a01, a10, a11, b0, b1, acc[0], acc[1]); PRIO(0);
        BAR();
        // ---- P2: quad1, stage A(T+1) h1 ----
        lda_quad(aR0, 1, koff0, koff1, a00, a01, a10, a11);
        STAGE_A(1, 1, T + 1);
        BAR(); WAITL(0);
        PRIO(1); mfma_quad(a00, a01, a10, a11, b0, b1, acc[2], acc[3]); PRIO(0);
        BAR();
        // ---- P3: quad2, stage B(T+2) h0 (Bs[0] freed after P1) ----
        lda_quad(aR0, 2, koff0, koff1, a00, a01, a10, a11);
        STAGE_B(0, 0, T + 2);
        BAR(); WAITL(0);
        PRIO(1); mfma_quad(a00, a01, a10, a11, b0, b1, acc[4], acc[5]); PRIO(0);
        BAR();
        // ---- P4: quad3, stage B(T+2) h1 ; counted vmcnt retires A(T+1) ----
        lda_quad(aR0, 3, koff0, koff1, a00, a01, a10, a11);
        STAGE_B(0, 1, T + 2);
        WAITV(4); BAR(); WAITL(0);
        PRIO(1); mfma_quad(a00, a01, a10, a11, b0, b1, acc[6], acc[7]); PRIO(0);
        BAR();
        // ---- P5: tile T+1 quad0 (+ B(T+1) frags), stage A(T+2) h0 (As[0] freed) ----
        ldb_all(bR1, koff0, koff1, b0, b1);
        lda_quad(aR1, 0, koff0, koff1, a00, a01, a10, a11);
        STAGE_A(0, 0, T + 2);
        WAITL(8); BAR(); WAITL(0);
        PRIO(1); mfma_quad(a00, a01, a10, a11, b0, b1, acc[0], acc[1]); PRIO(0);
        BAR();
        // ---- P6: quad1, stage A(T+2) h1 ----
        lda_quad(aR1, 1, koff0, koff1, a00, a01, a10, a11);
        STAGE_A(0, 1, T + 2);
        BAR(); WAITL(0);
        PRIO(1); mfma_quad(a00, a01, a10, a11, b0, b1, acc[2], acc[3]); PRIO(0);
        BAR();
        // ---- P7: quad2, stage B(T+3) h0 (Bs[1] freed after P5) ----
        lda_quad(aR1, 2, koff0, koff1, a00, a01, a10, a11);
        STAGE_B(1, 0, T + 3);
        BAR(); WAITL(0);
        PRIO(1); mfma_quad(a00, a01, a10, a11, b0, b1, acc[4], acc[5]); PRIO(0);
        BAR();
        // ---- P8: quad3, stage B(T+3) h1 ; counted vmcnt retires B(T+2)+A(T+2) ----
        lda_quad(aR1, 3, koff0, koff1, a00, a01, a10, a11);
        STAGE_B(1, 1, T + 3);
        WAITV(4); BAR(); WAITL(0);
        PRIO(1); mfma_quad(a00, a01, a10, a11, b0, b1, acc[6], acc[7]); PRIO(0);
        BAR();
    }

    // ---- peeled final iteration: tiles 30, 31 (counted wait invalid at tail) ----
    ldb_all(bR0, koff0, koff1, b0, b1);
    lda_quad(aR0, 0, koff0, koff1, a00, a01, a10, a11);
    STAGE_A(1, 0, 31);
    WAITL(8); BAR(); WAITL(0);
    PRIO(1); mfma_quad(a00, a01, a10, a11, b0, b1, acc[0], acc[1]); PRIO(0);
    BAR();
    lda_quad(aR0, 1, koff0, koff1, a00, a01, a10, a11);
    STAGE_A(1, 1, 31);
    BAR(); WAITL(0);
    PRIO(1); mfma_quad(a00, a01, a10, a11, b0, b1, acc[2], acc[3]); PRIO(0);
    BAR();
    lda_quad(aR0, 2, koff0, koff1, a00, a01, a10, a11);
    BAR(); WAITL(0);
    PRIO(1); mfma_quad(a00, a01, a10, a11, b0, b1, acc[4], acc[5]); PRIO(0);
    BAR();
    lda_quad(aR0, 3, koff0, koff1, a00, a01, a10, a11);
    WAITV(0); BAR(); WAITL(0);             // drain: A(31)+B(31) fully landed
    PRIO(1); mfma_quad(a00, a01, a10, a11, b0, b1, acc[6], acc[7]); PRIO(0);
    BAR();
    ldb_all(bR1, koff0, koff1, b0, b1);
    lda_quad(aR1, 0, koff0, koff1, a00, a01, a10, a11);
    BAR(); WAITL(0);
    PRIO(1); mfma_quad(a00, a01, a10, a11, b0, b1, acc[0], acc[1]); PRIO(0);
    BAR();
    lda_quad(aR1, 1, koff0, koff1, a00, a01, a10, a11);
    BAR(); WAITL(0);
    PRIO(1); mfma_quad(a00, a01, a10, a11, b0, b1, acc[2], acc[3]); PRIO(0);
    BAR();
    lda_quad(aR1, 2, koff0, koff1, a00, a01, a10, a11);
    BAR(); WAITL(0);
    PRIO(1); mfma_quad(a00, a01, a10, a11, b0, b1, acc[4], acc[5]); PRIO(0);
    BAR();
    lda_quad(aR1, 3, koff0, koff1, a00, a01, a10, a11);
    WAITL(0);
    PRIO(1); mfma_quad(a00, a01, a10, a11, b0, b1, acc[6], acc[7]); PRIO(0);

    // epilogue: C/D layout col=lane&15, row=quad*4+reg (m89-verified)
    #pragma unroll
    for (int m = 0; m < 8; ++m)
        #pragma unroll
        for (int n = 0; n < 4; ++n)
            #pragma unroll
            for (int j = 0; j < 4; ++j) {
                const int row = wm + m * 16 + q * 4 + j;
                const int col = wn + n * 16 + r;
                Cbase[(size_t)row * ND + col] = acc[m][n][j];
            }
}

// ---- Fallback (ws too small): fused fp32-staging kernel ----
#define LSTR 40
__global__ __launch_bounds__(256, 4) void fused_kernel(
    const float* __restrict__ A, const float* __restrict__ Bmat,
    float* __restrict__ C)
{
    __shared__ unsigned short Asf[BM][LSTR];
    __shared__ unsigned short Bsf[BN][LSTR];
    const int tid   = threadIdx.x;
    const int batch = blockIdx.z;
    const int row0  = blockIdx.y * BM;
    const int col0  = blockIdx.x * BN;
    const float* Abase = A    + (size_t)batch * MD * KD + (size_t)row0 * KD;
    const float* Bbase = Bmat + (size_t)batch * KD * ND + col0;
    float*       Cbase = C    + (size_t)batch * MD * ND + (size_t)row0 * ND + col0;
    const int a_row = tid >> 3, a_kc = (tid & 7) * 4;
    const int b_n = tid & 127, b_kh = (tid >> 7) * 16;
    const float* Bcol = Bbase + b_n;
    const int wave = tid >> 6, lane = tid & 63, q = lane >> 4, r = lane & 15;
    const int wm = (wave >> 1) * 64, wn = (wave & 1) * 64;
    f32x4 acc[4][4];
    #pragma unroll
    for (int i = 0; i < 4; ++i)
        #pragma unroll
        for (int j = 0; j < 4; ++j) acc[i][j] = (f32x4){0.f, 0.f, 0.f, 0.f};
    for (int k0 = 0; k0 < KD; k0 += 32) {
        #pragma unroll
        for (int i = 0; i < 4; ++i) {
            const int row = a_row + i * 32;
            const float4 v = *(const float4*)(Abase + (size_t)row * KD + k0 + a_kc);
            uint2 w; w.x = pk2(v.x, v.y); w.y = pk2(v.z, v.w);
            *(uint2*)&Asf[row][a_kc] = w;
        }
        #pragma unroll
        for (int h = 0; h < 2; ++h) {
            const int kb = b_kh + h * 8;
            float bv[8];
            #pragma unroll
            for (int j = 0; j < 8; ++j) bv[j] = Bcol[(size_t)(k0 + kb + j) * ND];
            uint4 w;
            w.x = pk2(bv[0], bv[1]); w.y = pk2(bv[2], bv[3]);
            w.z = pk2(bv[4], bv[5]); w.w = pk2(bv[6], bv[7]);
            *(uint4*)&Bsf[b_n][kb] = w;
        }
        __syncthreads();
        bf16x8 a_frag[4], b_frag[4];
        #pragma unroll
        for (int im = 0; im < 4; ++im)
            a_frag[im] = *(const bf16x8*)&Asf[wm + im * 16 + r][q * 8];
        #pragma unroll
        for (int in = 0; in < 4; ++in)
            b_frag[in] = *(const bf16x8*)&Bsf[wn + in * 16 + r][q * 8];
        #pragma unroll
        for (int im = 0; im < 4; ++im)
            #pragma unroll
            for (int in = 0; in < 4; ++in)
                acc[im][in] = MFMA16(a_frag[im], b_frag[in], acc[im][in]);
        __syncthreads();
    }
    #pragma unroll
    for (int im = 0; im < 4; ++im)
        #pragma unroll
        for (int in = 0; in < 4; ++in)
            #pragma unroll
            for (int j = 0; j < 4; ++j)
                Cbase[(size_t)(wm + im * 16 + q * 4 + j) * ND + wn + in * 16 + r]
                    = acc[im][in][j];
}

extern "C" void kernel_launch(void* const* d_in, const int* in_sizes, int n_in,
                              void* d_out, int out_size, void* d_ws, size_t ws_size,
                              hipStream_t stream) {
    const float* a = (const float*)d_in[0];
    const float* b = (const float*)d_in[1];
    float* out = (float*)d_out;

    const size_t abf_bytes = (size_t)NB * MD * KD * 2;   // 32 MB
    const size_t bt_bytes  = (size_t)NB * KD * ND * 2;   // 32 MB

    if (ws_size >= abf_bytes + bt_bytes) {
        unsigned short* Abf = (unsigned short*)d_ws;
        unsigned short* BT  = (unsigned short*)((char*)d_ws + abf_bytes);
        prep_kernel<<<dim3(NCAST + NB * (KD / 64) * (ND / 64)), dim3(256), 0, stream>>>(
            a, b, Abf, BT);
        gemm256_kernel<<<dim3(ND / 256, MD / 256, NB), dim3(512), 0, stream>>>(Abf, BT, out);
    } else {
        fused_kernel<<<dim3(ND / BN, MD / BM, NB), dim3(256), 0, stream>>>(a, b, out);
    }
}

// Round 2
// 239.254 us; speedup vs baseline: 1.0278x; 1.0278x over previous
//
#include <hip/hip_runtime.h>
#include <hip/hip_bf16.h>

#define NB   4
#define MD   2048
#define KD   2048
#define ND   2048

// fallback (fused) kernel tile
#define BM   128
#define BN   128

typedef short bf16x8 __attribute__((ext_vector_type(8)));
typedef float f32x4  __attribute__((ext_vector_type(4)));
typedef unsigned int u32;

#define MFMA16(a, b, c) __builtin_amdgcn_mfma_f32_16x16x32_bf16(a, b, c, 0, 0, 0)
#define BAR()    __builtin_amdgcn_s_barrier()
#define PRIO(n)  __builtin_amdgcn_s_setprio(n)
#define WAITV(n) asm volatile("s_waitcnt vmcnt(" #n ")" ::: "memory")
#define WAITL(n) asm volatile("s_waitcnt lgkmcnt(" #n ")" ::: "memory")
#define NOP      ((void)0)

// pack two fp32 -> one dword of 2 bf16 (RNE)
__device__ __forceinline__ unsigned pk2(float lo, float hi) {
    union { __hip_bfloat162 h2; unsigned u; } c;
    c.h2 = __float22bfloat162_rn(make_float2(lo, hi));
    return c.u;
}

__device__ __forceinline__ void gload_lds16(const void* g, void* l) {
    __builtin_amdgcn_global_load_lds(
        (const __attribute__((address_space(1))) u32*)g,
        (__attribute__((address_space(3))) u32*)l,
        16, 0, 0);
}

// ---- Phase 1 (fused): A fp32->bf16 cast (8 elem/thread)  +  B -> BT bf16 ----
#define NCAST ((NB * MD * KD / 8) / 256)   // 8192 cast blocks (uint4 out/thread)

__global__ __launch_bounds__(256) void prep_kernel(
    const float* __restrict__ A, const float* __restrict__ B,
    unsigned short* __restrict__ Abf, unsigned short* __restrict__ BT)
{
    __shared__ float t[64][65];   // transpose tile; +1 pad -> <=2-way conflicts (free)
    const int tid = threadIdx.x;

    if (blockIdx.x < NCAST) {
        const size_t idx = (size_t)blockIdx.x * 256 + tid;   // uint4 (8 bf16) index
        const float4 v0 = ((const float4*)A)[2 * idx];
        const float4 v1 = ((const float4*)A)[2 * idx + 1];
        uint4 w;
        w.x = pk2(v0.x, v0.y); w.y = pk2(v0.z, v0.w);
        w.z = pk2(v1.x, v1.y); w.w = pk2(v1.z, v1.w);
        ((uint4*)Abf)[idx] = w;
        return;
    }
    const int bx  = blockIdx.x - NCAST;      // 0..4095
    const int b   = bx >> 10;                // batch (1024 tiles per batch)
    const int rem = bx & 1023;
    const int k0  = (rem & 31) * 64;
    const int n0  = (rem >> 5) * 64;

    const float* Bb = B + (size_t)b * KD * ND;
    const int rk = tid >> 4;                 // 0..15, +16/pass
    const int rn = (tid & 15) * 4;
    #pragma unroll
    for (int p = 0; p < 4; ++p) {
        const int kl = p * 16 + rk;
        const float4 v = *(const float4*)(Bb + (size_t)(k0 + kl) * ND + n0 + rn);
        t[kl][rn + 0] = v.x; t[kl][rn + 1] = v.y;
        t[kl][rn + 2] = v.z; t[kl][rn + 3] = v.w;
    }
    __syncthreads();
    const int wn = tid >> 2;                 // 0..63 (owns column n)
    const int wk = (tid & 3) * 16;           // 16 consecutive k
    float f[16];
    #pragma unroll
    for (int j = 0; j < 16; ++j) f[j] = t[wk + j][wn];
    uint4 w0, w1;
    w0.x = pk2(f[0], f[1]);   w0.y = pk2(f[2], f[3]);
    w0.z = pk2(f[4], f[5]);   w0.w = pk2(f[6], f[7]);
    w1.x = pk2(f[8], f[9]);   w1.y = pk2(f[10], f[11]);
    w1.z = pk2(f[12], f[13]); w1.w = pk2(f[14], f[15]);
    unsigned short* dst = BT + (size_t)b * ND * KD + (size_t)(n0 + wn) * KD + k0 + wk;
    *(uint4*)(dst) = w0;
    *(uint4*)(dst + 8) = w1;
}

// ---------------------------------------------------------------------------
// Phase 2: 256x256 tile, BK=64, 8 waves (2M x 4N), 8-phase counted-vmcnt
// schedule. Round-2 changes vs round-1 (which measured 30% MfmaUtil = half of
// m201's 62%):
//  (a) k-slice-OUTER MFMA order: 8 independent MFMAs (k0) then 8 (k1) --
//      accumulator dependency distance 8, not 2.
//  (b) k1 fragment ds_reads issued after the leading barrier, overlapped
//      under the k0 MFMA cluster (pre-barrier LDS burst 6/2 instead of 12/4).
//  (c) XCD-bijective chunked blockIdx swizzle (256 wgs, %8==0): each XCD
//      gets a 4-row x 8-col slab of one batch -> A panels live in its L2.
// Ledger (unchanged): stage 1 half-tile (2 gloads)/phase; vmcnt(4) at P4
// retires A(T+1); vmcnt(4) at P8 retires B(T+2)+A(T+2); never 0 in main loop.
// ---------------------------------------------------------------------------

__device__ __forceinline__ void lda_pair(const unsigned short* aR, const int qd,
                                         const int koff, bf16x8& x0, bf16x8& x1)
{
    const unsigned short* p0 = aR + qd * (32 * 64);
    x0 = *(const bf16x8*)(p0 + koff);
    x1 = *(const bf16x8*)(p0 + 16 * 64 + koff);
}

__device__ __forceinline__ void ldb4(const unsigned short* bR, const int koff,
                                     bf16x8 (&b)[4])
{
    #pragma unroll
    for (int n = 0; n < 4; ++n)
        b[n] = *(const bf16x8*)(bR + n * (16 * 64) + koff);
}

// 8 independent MFMAs (one k-slice, both m-rows, all 4 n)
__device__ __forceinline__ void mfma8(const bf16x8& am0, const bf16x8& am1,
                                      const bf16x8 (&b)[4],
                                      f32x4 (&c0)[4], f32x4 (&c1)[4])
{
    #pragma unroll
    for (int n = 0; n < 4; ++n) c0[n] = MFMA16(am0, b[n], c0[n]);
    #pragma unroll
    for (int n = 0; n < 4; ++n) c1[n] = MFMA16(am1, b[n], c1[n]);
}

#define STAGE_A(buf, half, tile) do {                                               \
    const size_t kgA_ = (size_t)(tile) * 64;                                        \
    gload_lds16(Abase + (size_t)((half) * 128      + s_row) * KD + kgA_ + s_col,    \
                &As[buf][(half) * 128     ][0] + wave512);                          \
    gload_lds16(Abase + (size_t)((half) * 128 + 64 + s_row) * KD + kgA_ + s_col,    \
                &As[buf][(half) * 128 + 64][0] + wave512);                          \
} while (0)

#define STAGE_B(buf, half, tile) do {                                               \
    const size_t kgB_ = (size_t)(tile) * 64;                                        \
    gload_lds16(Bbase + (size_t)((half) * 128      + s_row) * KD + kgB_ + s_col,    \
                &Bs[buf][(half) * 128     ][0] + wave512);                          \
    gload_lds16(Bbase + (size_t)((half) * 128 + 64 + s_row) * KD + kgB_ + s_col,    \
                &Bs[buf][(half) * 128 + 64][0] + wave512);                          \
} while (0)

// generic phase (no B-frag reload): qd selects the m-quadrant
#define PHASE(aRp, qd, cA, cB, STG, PRE) do {                                       \
    lda_pair(aRp, qd, koff0, a00, a10);                                             \
    STG;                                                                            \
    PRE;                                                                            \
    BAR(); WAITL(0);                                                                \
    lda_pair(aRp, qd, koff1, a01, a11);                                             \
    PRIO(1);                                                                        \
    mfma8(a00, a10, b0, cA, cB);                                                    \
    WAITL(0);                                                                       \
    mfma8(a01, a11, b1, cA, cB);                                                    \
    PRIO(0);                                                                        \
    BAR();                                                                          \
} while (0)

// first phase of a tile: also (re)load the B fragments for this tile
#define PHASE_B(aRp, bRp, cA, cB, STG) do {                                         \
    ldb4(bRp, koff0, b0);                                                           \
    lda_pair(aRp, 0, koff0, a00, a10);                                              \
    STG;                                                                            \
    BAR(); WAITL(0);                                                                \
    ldb4(bRp, koff1, b1);                                                           \
    lda_pair(aRp, 0, koff1, a01, a11);                                              \
    PRIO(1);                                                                        \
    mfma8(a00, a10, b0, acc[0], acc[1]);                                            \
    WAITL(0);                                                                       \
    mfma8(a01, a11, b1, acc[0], acc[1]);                                            \
    PRIO(0);                                                                        \
    BAR();                                                                          \
} while (0)

__global__ __launch_bounds__(512, 2) void gemm256_kernel(
    const unsigned short* __restrict__ Abf, const unsigned short* __restrict__ BT,
    float* __restrict__ C)
{
    __shared__ __align__(16) unsigned short As[2][256][64];   // 64 KB
    __shared__ __align__(16) unsigned short Bs[2][256][64];   // 64 KB

    const int tid = threadIdx.x;

    // XCD-bijective chunked swizzle: 256 wgs, 8 XCDs, 32 wgs/XCD.
    // Each XCD's chunk = 4 row-panels x 8 col-panels of one batch (col fastest).
    const int wg    = blockIdx.x;
    const int lin   = ((wg & 7) << 5) | (wg >> 3);
    const int batch = lin >> 6;
    const int rem   = lin & 63;
    const int row0  = (rem >> 3) * 256;
    const int col0  = (rem & 7) * 256;

    const unsigned short* __restrict__ Abase =
        Abf + (size_t)batch * MD * KD + (size_t)row0 * KD;
    const unsigned short* __restrict__ Bbase =
        BT  + (size_t)batch * ND * KD + (size_t)col0 * KD;
    float* __restrict__ Cbase =
        C + (size_t)batch * MD * ND + (size_t)row0 * ND + col0;

    const int wave    = tid >> 6;
    const int lane    = tid & 63;
    const int q       = lane >> 4;          // 0..3
    const int r       = lane & 15;          // 0..15
    const int wm      = (wave >> 2) * 128;  // 0 / 128
    const int wn      = (wave & 3)  * 64;   // 0,64,128,192
    const int wave512 = wave * 512;         // elems: 1024 B per wave per 64-row round

    // staging geometry: per round 512 thr x 16 B = 64 rows x 128 B
    const int s_row = tid >> 3;                            // 0..63
    const int s_col = ((tid & 7) ^ (s_row & 7)) * 8;       // pre-swizzled src col (elems)

    // swizzled frag-read offsets (elems): logical slot ks*4+q -> ^ (r&7)
    const int rb    = r & 7;
    const int koff0 = ((q    ) ^ rb) * 8;                  // k-slice 0
    const int koff1 = ((4 + q) ^ rb) * 8;                  // k-slice 1

    const unsigned short* aR0 = &As[0][wm + r][0];
    const unsigned short* aR1 = &As[1][wm + r][0];
    const unsigned short* bR0 = &Bs[0][wn + r][0];
    const unsigned short* bR1 = &Bs[1][wn + r][0];

    f32x4 acc[8][4];
    #pragma unroll
    for (int m = 0; m < 8; ++m)
        #pragma unroll
        for (int n = 0; n < 4; ++n)
            acc[m][n] = (f32x4){0.f, 0.f, 0.f, 0.f};

    bf16x8 a00, a01, a10, a11;
    bf16x8 b0[4], b1[4];

    // prologue: tile0 A+B, tile1 B (A(1) is staged in P1/P2 of iteration 0)
    STAGE_A(0, 0, 0); STAGE_A(0, 1, 0);
    STAGE_B(0, 0, 0); STAGE_B(0, 1, 0);
    STAGE_B(1, 0, 1); STAGE_B(1, 1, 1);
    __syncthreads();                       // full drain once (prologue only)

    for (int it = 0; it < 15; ++it) {      // tiles T=2it, 2it+1 ; T <= 28
        const int T = it * 2;
        PHASE_B(aR0, bR0,    acc[0], acc[1], STAGE_A(1, 0, T + 1));
        PHASE  (aR0, 1,      acc[2], acc[3], STAGE_A(1, 1, T + 1), NOP);
        PHASE  (aR0, 2,      acc[4], acc[5], STAGE_B(0, 0, T + 2), NOP);
        PHASE  (aR0, 3,      acc[6], acc[7], STAGE_B(0, 1, T + 2), WAITV(4));
        PHASE_B(aR1, bR1,    acc[0], acc[1], STAGE_A(0, 0, T + 2));
        PHASE  (aR1, 1,      acc[2], acc[3], STAGE_A(0, 1, T + 2), NOP);
        PHASE  (aR1, 2,      acc[4], acc[5], STAGE_B(1, 0, T + 3), NOP);
        PHASE  (aR1, 3,      acc[6], acc[7], STAGE_B(1, 1, T + 3), WAITV(4));
    }

    // ---- peeled tail: tiles 30, 31 ----
    PHASE_B(aR0, bR0,    acc[0], acc[1], STAGE_A(1, 0, 31));
    PHASE  (aR0, 1,      acc[2], acc[3], STAGE_A(1, 1, 31), NOP);
    PHASE  (aR0, 2,      acc[4], acc[5], NOP, NOP);
    PHASE  (aR0, 3,      acc[6], acc[7], NOP, WAITV(0));   // drain: A(31)+B(31) landed
    PHASE_B(aR1, bR1,    acc[0], acc[1], NOP);
    PHASE  (aR1, 1,      acc[2], acc[3], NOP, NOP);
    PHASE  (aR1, 2,      acc[4], acc[5], NOP, NOP);
    PHASE  (aR1, 3,      acc[6], acc[7], NOP, NOP);

    // epilogue: C/D layout col=lane&15, row=quad*4+reg (m89-verified)
    #pragma unroll
    for (int m = 0; m < 8; ++m)
        #pragma unroll
        for (int n = 0; n < 4; ++n)
            #pragma unroll
            for (int j = 0; j < 4; ++j) {
                const int row = wm + m * 16 + q * 4 + j;
                const int col = wn + n * 16 + r;
                Cbase[(size_t)row * ND + col] = acc[m][n][j];
            }
}

// ---- Fallback (ws too small): fused fp32-staging kernel ----
#define LSTR 40
__global__ __launch_bounds__(256, 4) void fused_kernel(
    const float* __restrict__ A, const float* __restrict__ Bmat,
    float* __restrict__ C)
{
    __shared__ unsigned short Asf[BM][LSTR];
    __shared__ unsigned short Bsf[BN][LSTR];
    const int tid   = threadIdx.x;
    const int batch = blockIdx.z;
    const int row0  = blockIdx.y * BM;
    const int col0  = blockIdx.x * BN;
    const float* Abase = A    + (size_t)batch * MD * KD + (size_t)row0 * KD;
    const float* Bbase = Bmat + (size_t)batch * KD * ND + col0;
    float*       Cbase = C    + (size_t)batch * MD * ND + (size_t)row0 * ND + col0;
    const int a_row = tid >> 3, a_kc = (tid & 7) * 4;
    const int b_n = tid & 127, b_kh = (tid >> 7) * 16;
    const float* Bcol = Bbase + b_n;
    const int wave = tid >> 6, lane = tid & 63, q = lane >> 4, r = lane & 15;
    const int wm = (wave >> 1) * 64, wn = (wave & 1) * 64;
    f32x4 acc[4][4];
    #pragma unroll
    for (int i = 0; i < 4; ++i)
        #pragma unroll
        for (int j = 0; j < 4; ++j) acc[i][j] = (f32x4){0.f, 0.f, 0.f, 0.f};
    for (int k0 = 0; k0 < KD; k0 += 32) {
        #pragma unroll
        for (int i = 0; i < 4; ++i) {
            const int row = a_row + i * 32;
            const float4 v = *(const float4*)(Abase + (size_t)row * KD + k0 + a_kc);
            uint2 w; w.x = pk2(v.x, v.y); w.y = pk2(v.z, v.w);
            *(uint2*)&Asf[row][a_kc] = w;
        }
        #pragma unroll
        for (int h = 0; h < 2; ++h) {
            const int kb = b_kh + h * 8;
            float bv[8];
            #pragma unroll
            for (int j = 0; j < 8; ++j) bv[j] = Bcol[(size_t)(k0 + kb + j) * ND];
            uint4 w;
            w.x = pk2(bv[0], bv[1]); w.y = pk2(bv[2], bv[3]);
            w.z = pk2(bv[4], bv[5]); w.w = pk2(bv[6], bv[7]);
            *(uint4*)&Bsf[b_n][kb] = w;
        }
        __syncthreads();
        bf16x8 a_frag[4], b_frag[4];
        #pragma unroll
        for (int im = 0; im < 4; ++im)
            a_frag[im] = *(const bf16x8*)&Asf[wm + im * 16 + r][q * 8];
        #pragma unroll
        for (int in = 0; in < 4; ++in)
            b_frag[in] = *(const bf16x8*)&Bsf[wn + in * 16 + r][q * 8];
        #pragma unroll
        for (int im = 0; im < 4; ++im)
            #pragma unroll
            for (int in = 0; in < 4; ++in)
                acc[im][in] = MFMA16(a_frag[im], b_frag[in], acc[im][in]);
        __syncthreads();
    }
    #pragma unroll
    for (int im = 0; im < 4; ++im)
        #pragma unroll
        for (int in = 0; in < 4; ++in)
            #pragma unroll
            for (int j = 0; j < 4; ++j)
                Cbase[(size_t)(wm + im * 16 + q * 4 + j) * ND + wn + in * 16 + r]
                    = acc[im][in][j];
}

extern "C" void kernel_launch(void* const* d_in, const int* in_sizes, int n_in,
                              void* d_out, int out_size, void* d_ws, size_t ws_size,
                              hipStream_t stream) {
    const float* a = (const float*)d_in[0];
    const float* b = (const float*)d_in[1];
    float* out = (float*)d_out;

    const size_t abf_bytes = (size_t)NB * MD * KD * 2;   // 32 MB
    const size_t bt_bytes  = (size_t)NB * KD * ND * 2;   // 32 MB

    if (ws_size >= abf_bytes + bt_bytes) {
        unsigned short* Abf = (unsigned short*)d_ws;
        unsigned short* BT  = (unsigned short*)((char*)d_ws + abf_bytes);
        prep_kernel<<<dim3(NCAST + NB * (KD / 64) * (ND / 64)), dim3(256), 0, stream>>>(
            a, b, Abf, BT);
        const int nwg = (MD / 256) * (ND / 256) * NB;    // 256
        gemm256_kernel<<<dim3(nwg), dim3(512), 0, stream>>>(Abf, BT, out);
    } else {
        fused_kernel<<<dim3(ND / BN, MD / BM, NB), dim3(256), 0, stream>>>(a, b, out);
    }
}

// Round 3
// 221.417 us; speedup vs baseline: 1.1106x; 1.0806x over previous
//
#include <hip/hip_runtime.h>
#include <hip/hip_bf16.h>

#define NB   4
#define MD   2048
#define KD   2048
#define ND   2048

// fallback (fused) kernel tile
#define BM   128
#define BN   128

typedef short bf16x8 __attribute__((ext_vector_type(8)));
typedef float f32x4  __attribute__((ext_vector_type(4)));
typedef unsigned int u32;

#define MFMA16(a, b, c) __builtin_amdgcn_mfma_f32_16x16x32_bf16(a, b, c, 0, 0, 0)
#define BAR()    __builtin_amdgcn_s_barrier()
#define PRIO(n)  __builtin_amdgcn_s_setprio(n)
#define WAITV(n) asm volatile("s_waitcnt vmcnt(" #n ")" ::: "memory")
#define WAITL(n) asm volatile("s_waitcnt lgkmcnt(" #n ")" ::: "memory")
#define ESYNC    do { WAITV(0); BAR(); } while (0)
#define ENON     ((void)0)

// pack two fp32 -> one dword of 2 bf16 (RNE)
__device__ __forceinline__ unsigned pk2(float lo, float hi) {
    union { __hip_bfloat162 h2; unsigned u; } c;
    c.h2 = __float22bfloat162_rn(make_float2(lo, hi));
    return c.u;
}

__device__ __forceinline__ void gload_lds16(const void* g, void* l) {
    __builtin_amdgcn_global_load_lds(
        (const __attribute__((address_space(1))) u32*)g,
        (__attribute__((address_space(3))) u32*)l,
        16, 0, 0);
}

// ---- Phase 1 (fused): A fp32->bf16 cast (8 elem/thread)  +  B -> BT bf16 ----
#define NCAST ((NB * MD * KD / 8) / 256)   // 8192 cast blocks (uint4 out/thread)

__global__ __launch_bounds__(256) void prep_kernel(
    const float* __restrict__ A, const float* __restrict__ B,
    unsigned short* __restrict__ Abf, unsigned short* __restrict__ BT)
{
    __shared__ float t[64][65];   // transpose tile; +1 pad -> <=2-way conflicts (free)
    const int tid = threadIdx.x;

    if (blockIdx.x < NCAST) {
        const size_t idx = (size_t)blockIdx.x * 256 + tid;   // uint4 (8 bf16) index
        const float4 v0 = ((const float4*)A)[2 * idx];
        const float4 v1 = ((const float4*)A)[2 * idx + 1];
        uint4 w;
        w.x = pk2(v0.x, v0.y); w.y = pk2(v0.z, v0.w);
        w.z = pk2(v1.x, v1.y); w.w = pk2(v1.z, v1.w);
        ((uint4*)Abf)[idx] = w;
        return;
    }
    const int bx  = blockIdx.x - NCAST;      // 0..4095
    const int b   = bx >> 10;                // batch (1024 tiles per batch)
    const int rem = bx & 1023;
    const int k0  = (rem & 31) * 64;
    const int n0  = (rem >> 5) * 64;

    const float* Bb = B + (size_t)b * KD * ND;
    const int rk = tid >> 4;                 // 0..15, +16/pass
    const int rn = (tid & 15) * 4;
    #pragma unroll
    for (int p = 0; p < 4; ++p) {
        const int kl = p * 16 + rk;
        const float4 v = *(const float4*)(Bb + (size_t)(k0 + kl) * ND + n0 + rn);
        t[kl][rn + 0] = v.x; t[kl][rn + 1] = v.y;
        t[kl][rn + 2] = v.z; t[kl][rn + 3] = v.w;
    }
    __syncthreads();
    const int wn = tid >> 2;                 // 0..63 (owns column n)
    const int wk = (tid & 3) * 16;           // 16 consecutive k
    float f[16];
    #pragma unroll
    for (int j = 0; j < 16; ++j) f[j] = t[wk + j][wn];
    uint4 w0, w1;
    w0.x = pk2(f[0], f[1]);   w0.y = pk2(f[2], f[3]);
    w0.z = pk2(f[4], f[5]);   w0.w = pk2(f[6], f[7]);
    w1.x = pk2(f[8], f[9]);   w1.y = pk2(f[10], f[11]);
    w1.z = pk2(f[12], f[13]); w1.w = pk2(f[14], f[15]);
    unsigned short* dst = BT + (size_t)b * ND * KD + (size_t)(n0 + wn) * KD + k0 + wk;
    *(uint4*)(dst) = w0;
    *(uint4*)(dst + 8) = w1;
}

// ---------------------------------------------------------------------------
// Phase 2 (round 3): 256x256 tile, BK=64, 8 waves (2M x 4N), FAT phases.
//
// R2 post-mortem: 128 thin phases x 2 barriers = 1556 cyc/phase with only
// ~620 cyc of MFMA -> ~900 cyc/phase of lockstep sync overhead; MfmaUtil
// stuck at 32% regardless of intra-phase ordering. Fix: 4 phases per 2
// K-tiles (one phase = full K=32 slice of the wave's 128x64 output = 32
// independent MFMAs), barrier + vmcnt drain ONLY at buffer switches:
//   P1 [drain+bar] read buf0.s0 | stage A(2j+1)->As[1] | 32 MFMA
//   P2             read buf0.s1 | stage B(2j+1)->Bs[1] | 32 MFMA
//   P3 [drain+bar] read buf1.s0 | stage A(2j+2)->As[0] | 32 MFMA
//   P4             read buf1.s1 | stage B(2j+2)->Bs[0] | 32 MFMA
// 2 barriers / 128-k iteration (32 total vs 256 in R2). The entry drain
// retires loads issued >=1 phase (~2500 cyc) earlier -> near-zero stall
// (with lookahead=1 tile, counted vmcnt degenerates to drain: equivalent).
// Race ledger: every stage targets a buffer whose last reader's ds_reads
// completed (via its WAITL(0)) before that wave passed the intervening
// barrier. Keeps: T2 XOR swizzle (0 conflicts), XCD-bijective swizzle
// (FETCH 147->49 MB), setprio around MFMA clusters.
// ---------------------------------------------------------------------------

// Stage one full 256x64 tile: 4 rounds of (64 rows x 128 B), 512 thr x 16 B.
// LDS dest linear in tid (row=rr*64+tid/8, slot=tid%8 -> elem rr*4096+tid*8);
// global source column pre-swizzled (rule #21).
#define STAGE4(dst, buf, base, tile) do {                                    \
    _Pragma("unroll")                                                        \
    for (int rr_ = 0; rr_ < 4; ++rr_) {                                      \
        gload_lds16((base) + (size_t)(rr_ * 64 + s_row) * KD                 \
                           + (size_t)(tile) * 64 + s_col,                    \
                    &dst[buf][0][0] + rr_ * 4096 + tid * 8);                 \
    }                                                                        \
} while (0)

// One fat phase: 12 ds_read_b128 (4 B + 8 A frags), stage, 32 indep MFMA.
#define PHASE(bufi, ksi, ENTRY, STG) do {                                    \
    ENTRY;                                                                   \
    const unsigned short* aP_ = (bufi) ? aR1 : aR0;                          \
    const unsigned short* bP_ = (bufi) ? bR1 : bR0;                          \
    const int ko_ = (ksi) ? koff1 : koff0;                                   \
    bf16x8 bfr_[4], afr_[8];                                                 \
    _Pragma("unroll")                                                        \
    for (int n_ = 0; n_ < 4; ++n_)                                           \
        bfr_[n_] = *(const bf16x8*)(bP_ + n_ * (16 * 64) + ko_);             \
    _Pragma("unroll")                                                        \
    for (int m_ = 0; m_ < 8; ++m_)                                           \
        afr_[m_] = *(const bf16x8*)(aP_ + m_ * (16 * 64) + ko_);             \
    STG;                                                                     \
    WAITL(0);                                                                \
    PRIO(1);                                                                 \
    _Pragma("unroll")                                                        \
    for (int m_ = 0; m_ < 8; ++m_)                                           \
        _Pragma("unroll")                                                    \
        for (int n_ = 0; n_ < 4; ++n_)                                       \
            acc[m_][n_] = MFMA16(afr_[m_], bfr_[n_], acc[m_][n_]);           \
    PRIO(0);                                                                 \
} while (0)

__global__ __launch_bounds__(512, 2) void gemm256_kernel(
    const unsigned short* __restrict__ Abf, const unsigned short* __restrict__ BT,
    float* __restrict__ C)
{
    __shared__ __align__(16) unsigned short As[2][256][64];   // 64 KB
    __shared__ __align__(16) unsigned short Bs[2][256][64];   // 64 KB

    const int tid = threadIdx.x;

    // XCD-bijective chunked swizzle: 256 wgs, 8 XCDs, 32 wgs/XCD.
    const int wg    = blockIdx.x;
    const int lin   = ((wg & 7) << 5) | (wg >> 3);
    const int batch = lin >> 6;
    const int rem   = lin & 63;
    const int row0  = (rem >> 3) * 256;
    const int col0  = (rem & 7) * 256;

    const unsigned short* __restrict__ Abase =
        Abf + (size_t)batch * MD * KD + (size_t)row0 * KD;
    const unsigned short* __restrict__ Bbase =
        BT  + (size_t)batch * ND * KD + (size_t)col0 * KD;
    float* __restrict__ Cbase =
        C + (size_t)batch * MD * ND + (size_t)row0 * ND + col0;

    const int wave = tid >> 6;
    const int lane = tid & 63;
    const int q    = lane >> 4;          // 0..3
    const int r    = lane & 15;          // 0..15
    const int wm   = (wave >> 2) * 128;  // 0 / 128
    const int wn   = (wave & 3)  * 64;   // 0,64,128,192

    // staging geometry: per round 512 thr x 16 B = 64 rows x 128 B
    const int s_row = tid >> 3;                            // 0..63
    const int s_col = ((tid & 7) ^ (s_row & 7)) * 8;       // pre-swizzled src col (elems)

    // swizzled frag-read offsets (elems): logical slot ks*4+q -> ^ (r&7)
    const int rb    = r & 7;
    const int koff0 = ((q    ) ^ rb) * 8;                  // k-slice 0
    const int koff1 = ((4 + q) ^ rb) * 8;                  // k-slice 1

    const unsigned short* aR0 = &As[0][wm + r][0];
    const unsigned short* aR1 = &As[1][wm + r][0];
    const unsigned short* bR0 = &Bs[0][wn + r][0];
    const unsigned short* bR1 = &Bs[1][wn + r][0];

    f32x4 acc[8][4];
    #pragma unroll
    for (int m = 0; m < 8; ++m)
        #pragma unroll
        for (int n = 0; n < 4; ++n)
            acc[m][n] = (f32x4){0.f, 0.f, 0.f, 0.f};

    // prologue: tile 0 only; the rolling pattern stages tile 1 in P1/P2
    STAGE4(As, 0, Abase, 0);
    STAGE4(Bs, 0, Bbase, 0);

    for (int j = 0; j < 15; ++j) {       // tiles 2j, 2j+1 ; stages 2j+1, 2j+2
        PHASE(0, 0, ESYNC, STAGE4(As, 1, Abase, 2 * j + 1));
        PHASE(0, 1, ENON,  STAGE4(Bs, 1, Bbase, 2 * j + 1));
        PHASE(1, 0, ESYNC, STAGE4(As, 0, Abase, 2 * j + 2));
        PHASE(1, 1, ENON,  STAGE4(Bs, 0, Bbase, 2 * j + 2));
    }
    // peeled tail: tiles 30, 31 (no stage beyond tile 31)
    PHASE(0, 0, ESYNC, STAGE4(As, 1, Abase, 31));
    PHASE(0, 1, ENON,  STAGE4(Bs, 1, Bbase, 31));
    PHASE(1, 0, ESYNC, ENON);
    PHASE(1, 1, ENON,  ENON);

    // epilogue: C/D layout col=lane&15, row=quad*4+reg (m89-verified)
    #pragma unroll
    for (int m = 0; m < 8; ++m)
        #pragma unroll
        for (int n = 0; n < 4; ++n)
            #pragma unroll
            for (int j = 0; j < 4; ++j) {
                const int row = wm + m * 16 + q * 4 + j;
                const int col = wn + n * 16 + r;
                Cbase[(size_t)row * ND + col] = acc[m][n][j];
            }
}

// ---- Fallback (ws too small): fused fp32-staging kernel ----
#define LSTR 40
__global__ __launch_bounds__(256, 4) void fused_kernel(
    const float* __restrict__ A, const float* __restrict__ Bmat,
    float* __restrict__ C)
{
    __shared__ unsigned short Asf[BM][LSTR];
    __shared__ unsigned short Bsf[BN][LSTR];
    const int tid   = threadIdx.x;
    const int batch = blockIdx.z;
    const int row0  = blockIdx.y * BM;
    const int col0  = blockIdx.x * BN;
    const float* Abase = A    + (size_t)batch * MD * KD + (size_t)row0 * KD;
    const float* Bbase = Bmat + (size_t)batch * KD * ND + col0;
    float*       Cbase = C    + (size_t)batch * MD * ND + (size_t)row0 * ND + col0;
    const int a_row = tid >> 3, a_kc = (tid & 7) * 4;
    const int b_n = tid & 127, b_kh = (tid >> 7) * 16;
    const float* Bcol = Bbase + b_n;
    const int wave = tid >> 6, lane = tid & 63, q = lane >> 4, r = lane & 15;
    const int wm = (wave >> 1) * 64, wn = (wave & 1) * 64;
    f32x4 acc[4][4];
    #pragma unroll
    for (int i = 0; i < 4; ++i)
        #pragma unroll
        for (int j = 0; j < 4; ++j) acc[i][j] = (f32x4){0.f, 0.f, 0.f, 0.f};
    for (int k0 = 0; k0 < KD; k0 += 32) {
        #pragma unroll
        for (int i = 0; i < 4; ++i) {
            const int row = a_row + i * 32;
            const float4 v = *(const float4*)(Abase + (size_t)row * KD + k0 + a_kc);
            uint2 w; w.x = pk2(v.x, v.y); w.y = pk2(v.z, v.w);
            *(uint2*)&Asf[row][a_kc] = w;
        }
        #pragma unroll
        for (int h = 0; h < 2; ++h) {
            const int kb = b_kh + h * 8;
            float bv[8];
            #pragma unroll
            for (int j = 0; j < 8; ++j) bv[j] = Bcol[(size_t)(k0 + kb + j) * ND];
            uint4 w;
            w.x = pk2(bv[0], bv[1]); w.y = pk2(bv[2], bv[3]);
            w.z = pk2(bv[4], bv[5]); w.w = pk2(bv[6], bv[7]);
            *(uint4*)&Bsf[b_n][kb] = w;
        }
        __syncthreads();
        bf16x8 a_frag[4], b_frag[4];
        #pragma unroll
        for (int im = 0; im < 4; ++im)
            a_frag[im] = *(const bf16x8*)&Asf[wm + im * 16 + r][q * 8];
        #pragma unroll
        for (int in = 0; in < 4; ++in)
            b_frag[in] = *(const bf16x8*)&Bsf[wn + in * 16 + r][q * 8];
        #pragma unroll
        for (int im = 0; im < 4; ++im)
            #pragma unroll
            for (int in = 0; in < 4; ++in)
                acc[im][in] = MFMA16(a_frag[im], b_frag[in], acc[im][in]);
        __syncthreads();
    }
    #pragma unroll
    for (int im = 0; im < 4; ++im)
        #pragma unroll
        for (int in = 0; in < 4; ++in)
            #pragma unroll
            for (int j = 0; j < 4; ++j)
                Cbase[(size_t)(wm + im * 16 + q * 4 + j) * ND + wn + in * 16 + r]
                    = acc[im][in][j];
}

extern "C" void kernel_launch(void* const* d_in, const int* in_sizes, int n_in,
                              void* d_out, int out_size, void* d_ws, size_t ws_size,
                              hipStream_t stream) {
    const float* a = (const float*)d_in[0];
    const float* b = (const float*)d_in[1];
    float* out = (float*)d_out;

    const size_t abf_bytes = (size_t)NB * MD * KD * 2;   // 32 MB
    const size_t bt_bytes  = (size_t)NB * KD * ND * 2;   // 32 MB

    if (ws_size >= abf_bytes + bt_bytes) {
        unsigned short* Abf = (unsigned short*)d_ws;
        unsigned short* BT  = (unsigned short*)((char*)d_ws + abf_bytes);
        prep_kernel<<<dim3(NCAST + NB * (KD / 64) * (ND / 64)), dim3(256), 0, stream>>>(
            a, b, Abf, BT);
        const int nwg = (MD / 256) * (ND / 256) * NB;    // 256
        gemm256_kernel<<<dim3(nwg), dim3(512), 0, stream>>>(Abf, BT, out);
    } else {
        fused_kernel<<<dim3(ND / BN, MD / BM, NB), dim3(256), 0, stream>>>(a, b, out);
    }
}